// Round 1
// baseline (9441.679 us; speedup 1.0000x reference)
//
#include <hip/hip_runtime.h>
#include <hip/hip_bf16.h>
#include <math.h>

#define H 1024
#define BATCH 32
#define TSEQ 128
#define VOCAB 32000
#define NROWS (TSEQ*BATCH)   // 4096 rows (t*32+b)
#define NBLK 16              // blocks in persistent LSTM kernel
#define HPB 64               // h-indices per block (NBLK*HPB == H)

typedef float f32x4 __attribute__((ext_vector_type(4)));
typedef __bf16 bf16x8 __attribute__((ext_vector_type(8)));

struct Bar { unsigned count; unsigned gen; };

__device__ __forceinline__ unsigned short f2bf(float f) {
    union { float f; unsigned u; } v; v.f = f;
    unsigned r = v.u + 0x7fffu + ((v.u >> 16) & 1u);  // round-nearest-even
    return (unsigned short)(r >> 16);
}

// ---------------- fp32 -> bf16 convert (4-wide) ----------------
__global__ void f2bf4_k(const float* __restrict__ s, unsigned short* __restrict__ d, int n4) {
    int i = blockIdx.x * 256 + threadIdx.x;
    if (i >= n4) return;
    float4 v = reinterpret_cast<const float4*>(s)[i];
    ushort4 o;
    o.x = f2bf(v.x); o.y = f2bf(v.y); o.z = f2bf(v.z); o.w = f2bf(v.w);
    reinterpret_cast<ushort4*>(d)[i] = o;
}

// ---------------- embedding gather -> bf16 ----------------
__global__ void embed_k(const int* __restrict__ tok, const float* __restrict__ emb,
                        unsigned short* __restrict__ x, int n4) {
    int i = blockIdx.x * 256 + threadIdx.x;   // over NROWS * (H/4)
    if (i >= n4) return;
    int r  = i >> 8;            // H/4 == 256
    int k4 = (i & 255) << 2;
    float4 v = *reinterpret_cast<const float4*>(emb + (size_t)tok[r] * H + k4);
    ushort4 o; o.x = f2bf(v.x); o.y = f2bf(v.y); o.z = f2bf(v.z); o.w = f2bf(v.w);
    *reinterpret_cast<ushort4*>(x + (size_t)r * H + k4) = o;
}

// ---------------- per-layer state init (+barrier reset) ----------------
__global__ void init_state_k(const float* __restrict__ h0l, const float* __restrict__ c0l,
                             unsigned short* __restrict__ hping0, float* __restrict__ c_st,
                             float* __restrict__ h_st, Bar* bar) {
    int i = blockIdx.x * 256 + threadIdx.x;
    if (i == 0) { bar->count = 0; bar->gen = 0; }
    if (i < BATCH * H) {
        hping0[i] = f2bf(h0l[i]);
        c_st[i]   = c0l[i];
        h_st[i]   = h0l[i];
    }
}

// ---------------- GEMM: C[M,N] = A[M,K] * W[N,K]^T + bias ----------------
// A,W row-major bf16; direct-fragment loads (no LDS), 128x128 block tile.
__global__ __launch_bounds__(256) void gemm_bt(
    const unsigned short* __restrict__ A,
    const unsigned short* __restrict__ W,
    const float* __restrict__ b1, const float* __restrict__ b2,
    float* __restrict__ C, int M, int N, int K)
{
    int tid  = threadIdx.x;
    int wave = tid >> 6, lane = tid & 63, quad = lane >> 4, l16 = lane & 15;
    int wm = wave >> 1, wn = wave & 1;
    int m0 = blockIdx.y * 128 + wm * 64;
    int n0 = blockIdx.x * 128 + wn * 64;
    f32x4 acc[4][4] = {};
    const unsigned short* Ab = A + (size_t)(m0 + l16) * K + quad * 8;
    const unsigned short* Wb = W + (size_t)(n0 + l16) * K + quad * 8;
    for (int k0 = 0; k0 < K; k0 += 32) {
        bf16x8 a[4], b[4];
#pragma unroll
        for (int i = 0; i < 4; ++i)
            a[i] = *reinterpret_cast<const bf16x8*>(Ab + (size_t)i * 16 * K + k0);
#pragma unroll
        for (int i = 0; i < 4; ++i)
            b[i] = *reinterpret_cast<const bf16x8*>(Wb + (size_t)i * 16 * K + k0);
#pragma unroll
        for (int mi = 0; mi < 4; ++mi)
#pragma unroll
            for (int ni = 0; ni < 4; ++ni)
                acc[mi][ni] = __builtin_amdgcn_mfma_f32_16x16x32_bf16(a[mi], b[ni], acc[mi][ni], 0, 0, 0);
    }
#pragma unroll
    for (int mi = 0; mi < 4; ++mi) {
#pragma unroll
        for (int ni = 0; ni < 4; ++ni) {
            int n = n0 + ni * 16 + l16;
            float bias = (b1 ? b1[n] : 0.f) + (b2 ? b2[n] : 0.f);
#pragma unroll
            for (int r = 0; r < 4; ++r) {
                int m = m0 + mi * 16 + quad * 4 + r;
                C[(size_t)m * N + n] = acc[mi][ni][r] + bias;
            }
        }
    }
}

// ---------------- persistent LSTM layer (128 steps, 16-block barrier) ----------------
// Block bk owns h-indices [bk*HPB, bk*HPB+HPB); wave g computes gate g for those
// indices (w_hh rows g*H + hbase + j), so the cell update is block-local.
__global__ __launch_bounds__(256, 1) void lstm_layer_k(
    const float* __restrict__ gates_in,       // [T*B, 4H], includes bias
    const unsigned short* __restrict__ w_hh,  // [4H, H] bf16
    float* c_st, float* h_st,                 // [B*H] this layer
    unsigned short* h_ping,                   // [2][B*H] bf16 ping-pong
    unsigned short* __restrict__ h_all,       // [T*B, H] bf16 outputs
    Bar* bar)
{
    const int bk   = blockIdx.x;
    const int tid  = threadIdx.x;
    const int wave = tid >> 6;     // gate index 0..3 (i,f,g,o)
    const int lane = tid & 63;
    const int quad = lane >> 4;
    const int l16  = lane & 15;
    const int hbase = bk * HPB;

    __shared__ float sg[4][BATCH][HPB];   // 32 KB

    const unsigned short* wb = w_hh + ((size_t)(wave * H + hbase + l16)) * H + quad * 8;

    for (int t = 0; t < TSEQ; ++t) {
        const unsigned short* hin  = h_ping + (t & 1) * (BATCH * H);
        unsigned short*       hout = h_ping + ((t + 1) & 1) * (BATCH * H);

        // gates[m=0..31][nl=0..63] for gate `wave`: h(t-1) @ w_hh_slice^T
        f32x4 acc[2][4] = {};
        const unsigned short* ab = hin + (size_t)l16 * H + quad * 8;
        for (int k0 = 0; k0 < H; k0 += 32) {
            bf16x8 a[2], b[4];
#pragma unroll
            for (int i = 0; i < 2; ++i)
                a[i] = *reinterpret_cast<const bf16x8*>(ab + (size_t)i * 16 * H + k0);
#pragma unroll
            for (int i = 0; i < 4; ++i)
                b[i] = *reinterpret_cast<const bf16x8*>(wb + (size_t)i * 16 * H + k0);
#pragma unroll
            for (int mi = 0; mi < 2; ++mi)
#pragma unroll
                for (int ni = 0; ni < 4; ++ni)
                    acc[mi][ni] = __builtin_amdgcn_mfma_f32_16x16x32_bf16(a[mi], b[ni], acc[mi][ni], 0, 0, 0);
        }
        const float* gin = gates_in + (size_t)t * BATCH * (4 * H);
#pragma unroll
        for (int mi = 0; mi < 2; ++mi)
#pragma unroll
            for (int ni = 0; ni < 4; ++ni) {
                int nl   = ni * 16 + l16;
                int gcol = wave * H + hbase + nl;
#pragma unroll
                for (int r = 0; r < 4; ++r) {
                    int m = mi * 16 + quad * 4 + r;
                    sg[wave][m][nl] = acc[mi][ni][r] + gin[(size_t)m * 4 * H + gcol];
                }
            }
        __syncthreads();

        // cell update: 32*64 values, 8 per thread
        for (int e = tid; e < BATCH * HPB; e += 256) {
            int b  = e >> 6;           // / HPB
            int j  = e & (HPB - 1);
            int hj = hbase + j;
            float i_ = 1.f / (1.f + expf(-sg[0][b][j]));
            float f_ = 1.f / (1.f + expf(-sg[1][b][j]));
            float g_ = tanhf(sg[2][b][j]);
            float o_ = 1.f / (1.f + expf(-sg[3][b][j]));
            float c  = f_ * c_st[b * H + hj] + i_ * g_;
            c_st[b * H + hj] = c;
            float h  = o_ * tanhf(c);
            h_st[b * H + hj] = h;
            unsigned short hb = f2bf(h);
            hout[b * H + hj] = hb;
            h_all[(size_t)(t * BATCH + b) * H + hj] = hb;
        }

        // inter-block barrier (sense via generation counter)
        __threadfence();
        __syncthreads();
        if (tid == 0) {
            unsigned v = atomicAdd(&bar->count, 1u);
            if (v == NBLK - 1) {
                atomicExch(&bar->count, 0u);
                __threadfence();
                atomicAdd(&bar->gen, 1u);
            } else {
                while (atomicAdd(&bar->gen, 0u) < (unsigned)(t + 1))
                    __builtin_amdgcn_s_sleep(1);
            }
        }
        __syncthreads();
        __threadfence();
    }
}

// ---------------- in-place log_softmax, one block per row ----------------
__global__ __launch_bounds__(256) void logsoftmax_k(float* __restrict__ out) {
    float* p = out + (size_t)blockIdx.x * VOCAB;
    int tid = threadIdx.x;
    float m = -INFINITY, s = 0.f;
    for (int j = tid; j < VOCAB; j += 256) {     // 125 iters exactly
        float x = p[j];
        if (x > m) { s = s * expf(m - x) + 1.f; m = x; }
        else         s += expf(x - m);
    }
    __shared__ float sm[256], ss[256];
    sm[tid] = m; ss[tid] = s;
    __syncthreads();
    for (int off = 128; off > 0; off >>= 1) {
        if (tid < off) {
            float m2 = sm[tid + off], s2 = ss[tid + off];
            float M = fmaxf(sm[tid], m2);
            ss[tid] = ss[tid] * expf(sm[tid] - M) + s2 * expf(m2 - M);
            sm[tid] = M;
        }
        __syncthreads();
    }
    float L = sm[0] + logf(ss[0]);
    for (int j = tid; j < VOCAB; j += 256) p[j] -= L;
}

// ---------------- write hN / cN tail ----------------
__global__ void tail_k(const float* __restrict__ hs, const float* __restrict__ cs,
                       float* __restrict__ o) {
    int i = blockIdx.x * 256 + threadIdx.x;
    const int n = 2 * BATCH * H;
    if (i < n) { o[i] = hs[i]; o[n + i] = cs[i]; }
}

extern "C" void kernel_launch(void* const* d_in, const int* in_sizes, int n_in,
                              void* d_out, int out_size, void* d_ws, size_t ws_size,
                              hipStream_t stream)
{
    const int*   tokens = (const int*)  d_in[0];
    const float* h0     = (const float*)d_in[1];
    const float* c0     = (const float*)d_in[2];
    const float* emb    = (const float*)d_in[3];
    const float* w_ih   = (const float*)d_in[4];
    const float* w_hh   = (const float*)d_in[5];
    const float* b_ih   = (const float*)d_in[6];
    const float* b_hh   = (const float*)d_in[7];
    const float* w_dec  = (const float*)d_in[8];
    const float* b_dec  = (const float*)d_in[9];
    float* out = (float*)d_out;

    char* ws = (char*)d_ws;
    size_t off = 0;
    auto alloc = [&](size_t bytes) {
        char* p = ws + off;
        off += (bytes + 255) & ~(size_t)255;
        return p;
    };
    unsigned short* wihb  = (unsigned short*)alloc((size_t)2 * 4 * H * H * 2);
    unsigned short* whhb  = (unsigned short*)alloc((size_t)2 * 4 * H * H * 2);
    unsigned short* wdecb = (unsigned short*)alloc((size_t)VOCAB * H * 2);
    unsigned short* xbf   = (unsigned short*)alloc((size_t)NROWS * H * 2);
    unsigned short* h1bf  = (unsigned short*)alloc((size_t)NROWS * H * 2);
    unsigned short* h2bf  = (unsigned short*)alloc((size_t)NROWS * H * 2);
    float*          gates = (float*)alloc((size_t)NROWS * 4 * H * 4);
    unsigned short* hping = (unsigned short*)alloc((size_t)2 * BATCH * H * 2);
    float*          cst   = (float*)alloc((size_t)2 * BATCH * H * 4);
    float*          hst   = (float*)alloc((size_t)2 * BATCH * H * 4);
    Bar*            bar   = (Bar*)alloc(256);

    // weight / input conversion to bf16
    {
        int n4 = 2 * 4 * H * H / 4;
        f2bf4_k<<<(n4 + 255) / 256, 256, 0, stream>>>(w_ih, wihb, n4);
        f2bf4_k<<<(n4 + 255) / 256, 256, 0, stream>>>(w_hh, whhb, n4);
        int nd4 = VOCAB * H / 4;
        f2bf4_k<<<(nd4 + 255) / 256, 256, 0, stream>>>(w_dec, wdecb, nd4);
        int ne4 = NROWS * H / 4;
        embed_k<<<(ne4 + 255) / 256, 256, 0, stream>>>(tokens, emb, xbf, ne4);
    }

    for (int l = 0; l < 2; ++l) {
        const unsigned short* xin  = (l == 0) ? xbf : h1bf;
        unsigned short*       hall = (l == 0) ? h1bf : h2bf;
        init_state_k<<<(BATCH * H + 255) / 256, 256, 0, stream>>>(
            h0 + (size_t)l * BATCH * H, c0 + (size_t)l * BATCH * H,
            hping, cst + (size_t)l * BATCH * H, hst + (size_t)l * BATCH * H, bar);
        // gates_in = x @ w_ih^T + (b_ih + b_hh)
        gemm_bt<<<dim3(4 * H / 128, NROWS / 128), 256, 0, stream>>>(
            xin, wihb + (size_t)l * 4 * H * H,
            b_ih + (size_t)l * 4 * H, b_hh + (size_t)l * 4 * H,
            gates, NROWS, 4 * H, H);
        lstm_layer_k<<<NBLK, 256, 0, stream>>>(
            gates, whhb + (size_t)l * 4 * H * H,
            cst + (size_t)l * BATCH * H, hst + (size_t)l * BATCH * H,
            hping, hall, bar);
    }

    // decoder: logits -> d_out
    gemm_bt<<<dim3(VOCAB / 128, NROWS / 128), 256, 0, stream>>>(
        h2bf, wdecb, b_dec, nullptr, out, NROWS, VOCAB, H);
    logsoftmax_k<<<NROWS, 256, 0, stream>>>(out);
    tail_k<<<(2 * BATCH * H + 255) / 256, 256, 0, stream>>>(hst, cst, out + (size_t)NROWS * VOCAB);
}